// Round 2
// baseline (1330.941 us; speedup 1.0000x reference)
//
#include <hip/hip_runtime.h>

// TruncatedMLP fused edge-MLP for MI355X (gfx950).
//
// Design (round 1 resubmit — round 0/1 both failed on GPU-broker infra,
// no counters; kernel re-audited for OOB / capture hazards, none found):
//  - All GEMMs via v_mfma_f32_16x16x32_f16 with fp32->fp16 hi/lo split
//    (3 products: hh + hl + lh; error ~2^-22 relative, f32-equivalent).
//  - Kernel 1 (node_proj): P_src = src_feat@Ws^T, P_dst = dst_feat@Wd^T + b1
//    into d_ws (102.4 MB needed).
//  - Kernel 2 (edge, FUSED=false): per 64-edge tile:
//      stage efeat tile split-f16 in LDS (row stride 136 -> conflict-free
//      ds_read_b128), 8 waves x 16 output cols, weight frags in VGPRs,
//      GEMM1 -> +gather(P_src,P_dst from L3) -> SiLU -> split back to LDS
//      -> GEMM2 -> +b2 -> LayerNorm via cross-wave partial sums -> store.
//  - FUSED=true fallback (ws too small): gathers raw src/dst features and
//    runs 3 accumulating GEMMs in phase 1. Same epilogue.

typedef _Float16 f16x8 __attribute__((ext_vector_type(8)));
typedef float f32x4 __attribute__((ext_vector_type(4)));

#define DEV static __device__ __forceinline__

constexpr int D   = 128;   // all feature dims
constexpr int TM  = 64;    // tile rows (edges/nodes) per block
constexpr int NT  = 512;   // threads per block (8 waves)
constexpr int AST = 136;   // LDS A-tile row stride in f16 elems (272 B: conflict-free b128)

// ---- fp32 -> fp16 hi/lo split helpers -------------------------------------

DEV void split8(const float* __restrict__ x, f16x8& h, f16x8& l) {
#pragma unroll
  for (int i = 0; i < 8; ++i) {
    _Float16 hh = (_Float16)x[i];
    h[i] = hh;
    l[i] = (_Float16)(x[i] - (float)hh);
  }
}

// stage 16 consecutive floats of one row into split LDS tiles
DEV void stage16(const float* __restrict__ src, _Float16* __restrict__ sAh,
                 _Float16* __restrict__ sAl, int r, int seg) {
  const float4* p = (const float4*)src + seg * 4;
  float4 f0 = p[0], f1 = p[1], f2 = p[2], f3 = p[3];
  float x[16] = {f0.x, f0.y, f0.z, f0.w, f1.x, f1.y, f1.z, f1.w,
                 f2.x, f2.y, f2.z, f2.w, f3.x, f3.y, f3.z, f3.w};
  f16x8 vh0, vh1, vl0, vl1;
  split8(x, vh0, vl0);
  split8(x + 8, vh1, vl1);
  _Float16* dh = sAh + r * AST + seg * 16;
  _Float16* dl = sAl + r * AST + seg * 16;
  ((f16x8*)dh)[0] = vh0;
  ((f16x8*)dh)[1] = vh1;
  ((f16x8*)dl)[0] = vl0;
  ((f16x8*)dl)[1] = vl1;
}

// load one wave's B fragments (16 cols starting at nb) of W[128][128], split
DEV void load_w(const float* __restrict__ W, int nb, int lane, f16x8 bh[4], f16x8 bl[4]) {
  const int col = nb + (lane & 15);
  const int kb = (lane >> 4) * 8;
#pragma unroll
  for (int ks = 0; ks < 4; ++ks) {
    const float* p = W + col * D + ks * 32 + kb;
    float4 a = ((const float4*)p)[0];
    float4 b = ((const float4*)p)[1];
    float x[8] = {a.x, a.y, a.z, a.w, b.x, b.y, b.z, b.w};
    split8(x, bh[ks], bl[ks]);
  }
}

// one 64x16 GEMM slice: acc[mt] += Atile(64x128) * W(16 cols), split-f16 3-product
DEV void gemm16(const _Float16* __restrict__ sAh, const _Float16* __restrict__ sAl,
                const f16x8 bh[4], const f16x8 bl[4], int lane, f32x4 acc[4]) {
  const int r0 = lane & 15;
  const int kb = (lane >> 4) * 8;
#pragma unroll
  for (int ks = 0; ks < 4; ++ks) {
#pragma unroll
    for (int mt = 0; mt < 4; ++mt) {
      const int off = (mt * 16 + r0) * AST + ks * 32 + kb;
      f16x8 ah = *(const f16x8*)(sAh + off);
      f16x8 al = *(const f16x8*)(sAl + off);
      acc[mt] = __builtin_amdgcn_mfma_f32_16x16x32_f16(ah, bh[ks], acc[mt], 0, 0, 0);
      acc[mt] = __builtin_amdgcn_mfma_f32_16x16x32_f16(ah, bl[ks], acc[mt], 0, 0, 0);
      acc[mt] = __builtin_amdgcn_mfma_f32_16x16x32_f16(al, bh[ks], acc[mt], 0, 0, 0);
    }
  }
}

// ---- kernel 1: node projections -------------------------------------------

__global__ __launch_bounds__(NT) void node_proj_kernel(
    const float* __restrict__ src_feat, const float* __restrict__ dst_feat,
    const float* __restrict__ Ws, const float* __restrict__ Wd,
    const float* __restrict__ b1, float* __restrict__ Psrc,
    float* __restrict__ Pdst, int N) {
  __shared__ __align__(16) _Float16 sAh[TM * AST];
  __shared__ __align__(16) _Float16 sAl[TM * AST];
  const int t = threadIdx.x, lane = t & 63, w = t >> 6;
  const int nb = w * 16;
  const int tile = blockIdx.x * TM;
  const int r = t >> 3, seg = t & 7;
  const int cl = lane & 15, rg = lane >> 4;
  const int rowg = min(tile + r, N - 1);
  f16x8 bh[4], bl[4];

  // ---- src branch
  stage16(src_feat + (size_t)rowg * D, sAh, sAl, r, seg);
  load_w(Ws, nb, lane, bh, bl);
  __syncthreads();
  {
    f32x4 acc[4] = {};
    gemm16(sAh, sAl, bh, bl, lane, acc);
#pragma unroll
    for (int mt = 0; mt < 4; ++mt)
#pragma unroll
      for (int i = 0; i < 4; ++i) {
        int row = mt * 16 + rg * 4 + i, n = tile + row;
        if (n < N) Psrc[(size_t)n * D + nb + cl] = acc[mt][i];
      }
  }
  __syncthreads();
  // ---- dst branch (+b1)
  stage16(dst_feat + (size_t)rowg * D, sAh, sAl, r, seg);
  load_w(Wd, nb, lane, bh, bl);
  __syncthreads();
  {
    f32x4 acc[4] = {};
    gemm16(sAh, sAl, bh, bl, lane, acc);
    const float b1c = b1[nb + cl];
#pragma unroll
    for (int mt = 0; mt < 4; ++mt)
#pragma unroll
      for (int i = 0; i < 4; ++i) {
        int row = mt * 16 + rg * 4 + i, n = tile + row;
        if (n < N) Pdst[(size_t)n * D + nb + cl] = acc[mt][i] + b1c;
      }
  }
}

// ---- kernel 2: edge MLP ----------------------------------------------------

template <bool FUSED>
__global__ __launch_bounds__(NT) void edge_kernel(
    const float* __restrict__ efeat,
    const float* __restrict__ SrcP,  // FUSED ? src_feat : P_src
    const float* __restrict__ DstP,  // FUSED ? dst_feat : P_dst
    const int* __restrict__ src_idx, const int* __restrict__ dst_idx,
    const float* __restrict__ We, const float* __restrict__ Wsrc,
    const float* __restrict__ Wdst, const float* __restrict__ b1,
    const float* __restrict__ W2, const float* __restrict__ b2,
    const float* __restrict__ gamma, const float* __restrict__ beta,
    float* __restrict__ out, int E) {
  __shared__ __align__(16) _Float16 sAh[TM * AST];
  __shared__ __align__(16) _Float16 sAl[TM * AST];
  __shared__ int sSi[TM], sDi[TM];
  __shared__ float sRs[TM * 9], sRs2[TM * 9];

  const int t = threadIdx.x, lane = t & 63, w = t >> 6;
  const int nb = w * 16;
  const int tile = blockIdx.x * TM;
  const int r = t >> 3, seg = t & 7;
  const int cl = lane & 15, rg = lane >> 4;

  if (t < TM) {
    int e = min(tile + t, E - 1);
    sSi[t] = src_idx[e];
    sDi[t] = dst_idx[e];
  }
  {
    int e = min(tile + r, E - 1);
    stage16(efeat + (size_t)e * D, sAh, sAl, r, seg);
  }
  f16x8 bh[4], bl[4];
  load_w(We, nb, lane, bh, bl);
  __syncthreads();

  f32x4 acc[4] = {};
  gemm16(sAh, sAl, bh, bl, lane, acc);

  if constexpr (FUSED) {
    __syncthreads();
    stage16(SrcP + (size_t)sSi[r] * D, sAh, sAl, r, seg);
    load_w(Wsrc, nb, lane, bh, bl);
    __syncthreads();
    gemm16(sAh, sAl, bh, bl, lane, acc);
    __syncthreads();
    stage16(DstP + (size_t)sDi[r] * D, sAh, sAl, r, seg);
    load_w(Wdst, nb, lane, bh, bl);
    __syncthreads();
    gemm16(sAh, sAl, bh, bl, lane, acc);
  }

  // ---- epilogue 1: hidden = silu(acc + gathered node projections [+ b1])
  if constexpr (FUSED) {
    const float b1c = b1[nb + cl];
#pragma unroll
    for (int mt = 0; mt < 4; ++mt)
#pragma unroll
      for (int i = 0; i < 4; ++i) {
        float xx = acc[mt][i] + b1c;
        acc[mt][i] = xx / (1.f + __expf(-xx));
      }
  } else {
#pragma unroll
    for (int mt = 0; mt < 4; ++mt)
#pragma unroll
      for (int i = 0; i < 4; ++i) {
        int row = mt * 16 + rg * 4 + i;
        float g = SrcP[(size_t)sSi[row] * D + nb + cl] +
                  DstP[(size_t)sDi[row] * D + nb + cl];
        float xx = acc[mt][i] + g;
        acc[mt][i] = xx / (1.f + __expf(-xx));
      }
  }
  __syncthreads();  // all waves done reading A1 before overwrite

  // write split hidden back into the A tile
#pragma unroll
  for (int mt = 0; mt < 4; ++mt)
#pragma unroll
    for (int i = 0; i < 4; ++i) {
      int row = mt * 16 + rg * 4 + i;
      float xx = acc[mt][i];
      _Float16 h = (_Float16)xx;
      sAh[row * AST + nb + cl] = h;
      sAl[row * AST + nb + cl] = (_Float16)(xx - (float)h);
    }
  load_w(W2, nb, lane, bh, bl);
  __syncthreads();

  f32x4 acc2[4] = {};
  gemm16(sAh, sAl, bh, bl, lane, acc2);

  // ---- epilogue 2: +b2, LayerNorm(128) via cross-wave partials
  const float b2c = b2[nb + cl];
#pragma unroll
  for (int mt = 0; mt < 4; ++mt)
#pragma unroll
    for (int i = 0; i < 4; ++i) {
      float xx = acc2[mt][i] + b2c;
      acc2[mt][i] = xx;
      float s = xx, s2 = xx * xx;
      s += __shfl_xor(s, 1);  s2 += __shfl_xor(s2, 1);
      s += __shfl_xor(s, 2);  s2 += __shfl_xor(s2, 2);
      s += __shfl_xor(s, 4);  s2 += __shfl_xor(s2, 4);
      s += __shfl_xor(s, 8);  s2 += __shfl_xor(s2, 8);
      if (cl == 0) {
        int row = mt * 16 + rg * 4 + i;
        sRs[row * 9 + w] = s;   // stride 9: bank-spread
        sRs2[row * 9 + w] = s2;
      }
    }
  __syncthreads();

  float mu, rstd;
  {
    float s = 0.f, s2 = 0.f;
#pragma unroll
    for (int j = 0; j < 8; ++j) {
      s += sRs[lane * 9 + j];
      s2 += sRs2[lane * 9 + j];
    }
    mu = s * (1.f / 128.f);
    float var = s2 * (1.f / 128.f) - mu * mu;
    rstd = 1.f / sqrtf(var + 1e-5f);
  }
  const float gm = gamma[nb + cl], bt = beta[nb + cl];
#pragma unroll
  for (int mt = 0; mt < 4; ++mt)
#pragma unroll
    for (int i = 0; i < 4; ++i) {
      int row = mt * 16 + rg * 4 + i;
      float m = __shfl(mu, row);
      float rs = __shfl(rstd, row);
      int e = tile + row;
      if (e < E) out[(size_t)e * D + nb + cl] = (acc2[mt][i] - m) * rs * gm + bt;
    }
}

// ---- launch ----------------------------------------------------------------

extern "C" void kernel_launch(void* const* d_in, const int* in_sizes, int n_in,
                              void* d_out, int out_size, void* d_ws, size_t ws_size,
                              hipStream_t stream) {
  const float* efeat    = (const float*)d_in[0];
  const float* src_feat = (const float*)d_in[1];
  const float* dst_feat = (const float*)d_in[2];
  const int*   src_idx  = (const int*)d_in[3];
  const int*   dst_idx  = (const int*)d_in[4];
  const float* w_efeat  = (const float*)d_in[5];
  const float* w_src    = (const float*)d_in[6];
  const float* w_dst    = (const float*)d_in[7];
  const float* b1       = (const float*)d_in[8];
  const float* w2       = (const float*)d_in[9];
  const float* b2       = (const float*)d_in[10];
  const float* gamma    = (const float*)d_in[11];
  const float* beta     = (const float*)d_in[12];
  float* out = (float*)d_out;

  const int E = in_sizes[3];
  const int N = in_sizes[1] / D;
  const size_t needP = (size_t)2 * (size_t)N * D * sizeof(float);
  const int egrid = (E + TM - 1) / TM;

  if (ws_size >= needP) {
    float* Psrc = (float*)d_ws;
    float* Pdst = Psrc + (size_t)N * D;
    const int ngrid = (N + TM - 1) / TM;
    node_proj_kernel<<<ngrid, NT, 0, stream>>>(src_feat, dst_feat, w_src, w_dst,
                                               b1, Psrc, Pdst, N);
    edge_kernel<false><<<egrid, NT, 0, stream>>>(
        efeat, Psrc, Pdst, src_idx, dst_idx, w_efeat, nullptr, nullptr, nullptr,
        w2, b2, gamma, beta, out, E);
  } else {
    edge_kernel<true><<<egrid, NT, 0, stream>>>(
        efeat, src_feat, dst_feat, src_idx, dst_idx, w_efeat, w_src, w_dst, b1,
        w2, b2, gamma, beta, out, E);
  }
}